// Round 1
// baseline (701.059 us; speedup 1.0000x reference)
//
#include <hip/hip_runtime.h>

#define NPIX 1024
#define CC   512
#define DK   64

// ---------------------------------------------------------------------------
// pos[h,d,n] = rel_h[h,d, n%32] + rel_w[h,d, n/32]   (n = x*32 + y)
// ---------------------------------------------------------------------------
__global__ void pos_kernel(const float* __restrict__ rel_h,
                           const float* __restrict__ rel_w,
                           float* __restrict__ pos) {
  int idx = blockIdx.x * 256 + threadIdx.x;   // grid sized exactly 8*64*1024
  int n  = idx & (NPIX - 1);
  int hd = idx >> 10;                         // h*64 + d
  int xw = n >> 5;
  int yh = n & 31;
  pos[idx] = rel_h[hd * 32 + yh] + rel_w[hd * 32 + xw];
}

// ---------------------------------------------------------------------------
// Projection GEMM: Y[o,n] = sum_c W[o,c] * X[c,n] + bias[o]
// X = x[b] (512 x 1024), W (512 x 512).  BM=BN=128, BK=16, 256 thr, 8x8 micro
// blockIdx.z = b*3 + p   (p: 0=q 1=k 2=v)
// ---------------------------------------------------------------------------
__global__ __launch_bounds__(256) void proj_kernel(
    const float* __restrict__ x,
    const float* __restrict__ wq, const float* __restrict__ bq,
    const float* __restrict__ wk, const float* __restrict__ bk,
    const float* __restrict__ wv, const float* __restrict__ bv,
    float* __restrict__ qws, float* __restrict__ kws, float* __restrict__ vws) {
  __shared__ __align__(16) float sW[16][128];
  __shared__ __align__(16) float sX[16][128];

  int tid = threadIdx.x;
  int z = blockIdx.z;
  int b = z / 3, p = z % 3;
  const float* W    = (p == 0) ? wq : (p == 1) ? wk : wv;
  const float* bias = (p == 0) ? bq : (p == 1) ? bk : bv;
  float* out = ((p == 0) ? qws : (p == 1) ? kws : vws) + (size_t)b * CC * NPIX;
  const float* X = x + (size_t)b * CC * NPIX;

  int o0 = blockIdx.y * 128;
  int n0 = blockIdx.x * 128;

  float acc[8][8];
#pragma unroll
  for (int i = 0; i < 8; ++i)
#pragma unroll
    for (int j = 0; j < 8; ++j) acc[i][j] = 0.f;

  int ty = tid >> 4;   // 0..15 (o dir)
  int tx = tid & 15;   // 0..15 (n dir)

  for (int c0 = 0; c0 < CC; c0 += 16) {
    // W tile -> sW[kk][o]  (transposed store)
#pragma unroll
    for (int u = 0; u < 2; ++u) {
      int lin = tid * 2 + u;          // 0..511 float4 index
      int o = lin >> 2, cq = lin & 3;
      float4 w4 = *(const float4*)&W[(o0 + o) * CC + c0 + cq * 4];
      sW[cq * 4 + 0][o] = w4.x;
      sW[cq * 4 + 1][o] = w4.y;
      sW[cq * 4 + 2][o] = w4.z;
      sW[cq * 4 + 3][o] = w4.w;
    }
    // X tile -> sX[kk][n]
#pragma unroll
    for (int u = 0; u < 2; ++u) {
      int lin = tid * 2 + u;
      int kk = lin >> 5, nq = lin & 31;
      *(float4*)&sX[kk][nq * 4] =
          *(const float4*)&X[(c0 + kk) * NPIX + n0 + nq * 4];
    }
    __syncthreads();

#pragma unroll
    for (int kk = 0; kk < 16; ++kk) {
      float4 a0 = *(const float4*)&sW[kk][ty * 8];
      float4 a1 = *(const float4*)&sW[kk][ty * 8 + 4];
      float4 b0 = *(const float4*)&sX[kk][tx * 8];
      float4 b1 = *(const float4*)&sX[kk][tx * 8 + 4];
      float a[8] = {a0.x, a0.y, a0.z, a0.w, a1.x, a1.y, a1.z, a1.w};
      float bb[8] = {b0.x, b0.y, b0.z, b0.w, b1.x, b1.y, b1.z, b1.w};
#pragma unroll
      for (int i = 0; i < 8; ++i)
#pragma unroll
        for (int j = 0; j < 8; ++j) acc[i][j] = fmaf(a[i], bb[j], acc[i][j]);
    }
    __syncthreads();
  }

#pragma unroll
  for (int i = 0; i < 8; ++i) {
    int o = o0 + ty * 8 + i;
    float bv_ = bias[o];
    float4 r0, r1;
    r0.x = acc[i][0] + bv_; r0.y = acc[i][1] + bv_;
    r0.z = acc[i][2] + bv_; r0.w = acc[i][3] + bv_;
    r1.x = acc[i][4] + bv_; r1.y = acc[i][5] + bv_;
    r1.z = acc[i][6] + bv_; r1.w = acc[i][7] + bv_;
    *(float4*)&out[(size_t)o * NPIX + n0 + tx * 8]     = r0;
    *(float4*)&out[(size_t)o * NPIX + n0 + tx * 8 + 4] = r1;
  }
}

// ---------------------------------------------------------------------------
// Fused attention. One block = one (b,h) and 64 queries.
// A[d,q] = [Q;P] (128x64) staged once.  Stream 64-key chunks: B=[K;Q], V.
// S[q,k] = sum_d A[d,q]B[d,k]; online softmax over k; O[q,d] += P.V^T.
// Threads: 256 = 16 qg (4 q each) x 16 kt (4 k each).
// ---------------------------------------------------------------------------
__global__ __launch_bounds__(256) void attn_kernel(
    const float* __restrict__ qws, const float* __restrict__ kws,
    const float* __restrict__ vws, const float* __restrict__ pos,
    float* __restrict__ out) {
  __shared__ __align__(16) float sA[128][68];
  __shared__ __align__(16) float sB[128][68];
  __shared__ __align__(16) float sV[64][68];
  __shared__ __align__(16) float sP[64][68];

  int tid = threadIdx.x;
  int qb = blockIdx.x;           // 0..15
  int h = blockIdx.y, b = blockIdx.z;
  int n0 = qb * 64;

  const float* Qbh = qws + ((size_t)b * CC + h * DK) * NPIX;
  const float* Kbh = kws + ((size_t)b * CC + h * DK) * NPIX;
  const float* Vbh = vws + ((size_t)b * CC + h * DK) * NPIX;
  const float* Pbh = pos + (size_t)(h * DK) * NPIX;

  // stage A (once): rows 0..63 = Q, rows 64..127 = pos   (columns n0..n0+63)
#pragma unroll
  for (int u = 0; u < 8; ++u) {
    int lin = u * 256 + tid;     // 0..2047 float4 index
    int d = lin >> 4;
    int q4 = lin & 15;
    const float* src = (d < 64) ? &Qbh[d * NPIX + n0 + q4 * 4]
                                : &Pbh[(d - 64) * NPIX + n0 + q4 * 4];
    *(float4*)&sA[d][q4 * 4] = *(const float4*)src;
  }

  int qg = tid >> 4;   // 0..15
  int kt = tid & 15;   // 0..15

  float m_[4], l_[4], O[4][4];
#pragma unroll
  for (int i = 0; i < 4; ++i) {
    m_[i] = -1e30f;
    l_[i] = 0.f;
#pragma unroll
    for (int j = 0; j < 4; ++j) O[i][j] = 0.f;
  }

  for (int k0 = 0; k0 < NPIX; k0 += 64) {
    // stage B: rows 0..63 = K, rows 64..127 = Q   (columns k0..k0+63)
#pragma unroll
    for (int u = 0; u < 8; ++u) {
      int lin = u * 256 + tid;
      int d = lin >> 4, k4 = lin & 15;
      const float* src = (d < 64) ? &Kbh[d * NPIX + k0 + k4 * 4]
                                  : &Qbh[(d - 64) * NPIX + k0 + k4 * 4];
      *(float4*)&sB[d][k4 * 4] = *(const float4*)src;
    }
    // stage V
#pragma unroll
    for (int u = 0; u < 4; ++u) {
      int lin = u * 256 + tid;
      int d = lin >> 4, k4 = lin & 15;
      *(float4*)&sV[d][k4 * 4] =
          *(const float4*)&Vbh[d * NPIX + k0 + k4 * 4];
    }
    __syncthreads();

    // ---- S = A^T B (4x4 per thread, K=128) ----
    float s[4][4];
#pragma unroll
    for (int i = 0; i < 4; ++i)
#pragma unroll
      for (int j = 0; j < 4; ++j) s[i][j] = 0.f;

#pragma unroll 8
    for (int kk = 0; kk < 128; ++kk) {
      float4 a4 = *(const float4*)&sA[kk][qg * 4];
      float4 b4 = *(const float4*)&sB[kk][kt * 4];
      float a[4] = {a4.x, a4.y, a4.z, a4.w};
      float bb[4] = {b4.x, b4.y, b4.z, b4.w};
#pragma unroll
      for (int i = 0; i < 4; ++i)
#pragma unroll
        for (int j = 0; j < 4; ++j) s[i][j] = fmaf(a[i], bb[j], s[i][j]);
    }

    // ---- online softmax over this chunk ----
#pragma unroll
    for (int i = 0; i < 4; ++i) {
      float v = fmaxf(fmaxf(s[i][0], s[i][1]), fmaxf(s[i][2], s[i][3]));
#pragma unroll
      for (int off = 1; off < 16; off <<= 1) v = fmaxf(v, __shfl_xor(v, off, 64));
      float mn = fmaxf(m_[i], v);
      float sc = __expf(m_[i] - mn);
      float p[4];
      float ps = 0.f;
#pragma unroll
      for (int j = 0; j < 4; ++j) { p[j] = __expf(s[i][j] - mn); ps += p[j]; }
#pragma unroll
      for (int off = 1; off < 16; off <<= 1) ps += __shfl_xor(ps, off, 64);
      l_[i] = l_[i] * sc + ps;
      m_[i] = mn;
#pragma unroll
      for (int j = 0; j < 4; ++j) {
        O[i][j] *= sc;
        sP[qg * 4 + i][kt * 4 + j] = p[j];
      }
    }
    __syncthreads();

    // ---- O += P . V^T   (thread owns q = qg*4+i, d = kt+16*j) ----
#pragma unroll 4
    for (int k4 = 0; k4 < 16; ++k4) {
      float4 pv[4], vv[4];
#pragma unroll
      for (int i = 0; i < 4; ++i) pv[i] = *(const float4*)&sP[qg * 4 + i][k4 * 4];
#pragma unroll
      for (int j = 0; j < 4; ++j) vv[j] = *(const float4*)&sV[kt + 16 * j][k4 * 4];
#pragma unroll
      for (int i = 0; i < 4; ++i)
#pragma unroll
        for (int j = 0; j < 4; ++j) {
          O[i][j] = fmaf(pv[i].x, vv[j].x, O[i][j]);
          O[i][j] = fmaf(pv[i].y, vv[j].y, O[i][j]);
          O[i][j] = fmaf(pv[i].z, vv[j].z, O[i][j]);
          O[i][j] = fmaf(pv[i].w, vv[j].w, O[i][j]);
        }
    }
    __syncthreads();
  }

  // finalize: divide by l, transpose through LDS (reuse sB), coalesced store
  float (*sO)[68] = sB;
#pragma unroll
  for (int i = 0; i < 4; ++i) {
    float inv = 1.f / l_[i];
#pragma unroll
    for (int j = 0; j < 4; ++j) sO[kt + 16 * j][qg * 4 + i] = O[i][j] * inv;
  }
  __syncthreads();

#pragma unroll
  for (int u = 0; u < 4; ++u) {
    int lin = u * 256 + tid;       // 0..1023 float4 index
    int d = lin >> 4, q4 = lin & 15;
    float4 v4 = *(const float4*)&sO[d][q4 * 4];
    *(float4*)&out[((size_t)b * CC + h * DK + d) * NPIX + n0 + q4 * 4] = v4;
  }
}

// ---------------------------------------------------------------------------
extern "C" void kernel_launch(void* const* d_in, const int* in_sizes, int n_in,
                              void* d_out, int out_size, void* d_ws, size_t ws_size,
                              hipStream_t stream) {
  const float* x     = (const float*)d_in[0];
  const float* wq    = (const float*)d_in[1];
  const float* bq    = (const float*)d_in[2];
  const float* wk    = (const float*)d_in[3];
  const float* bk    = (const float*)d_in[4];
  const float* wv    = (const float*)d_in[5];
  const float* bv    = (const float*)d_in[6];
  const float* rel_h = (const float*)d_in[7];
  const float* rel_w = (const float*)d_in[8];
  float* out = (float*)d_out;

  float* qws = (float*)d_ws;                 // 8*512*1024 floats
  float* kws = qws + (size_t)8 * CC * NPIX;
  float* vws = kws + (size_t)8 * CC * NPIX;
  float* pws = vws + (size_t)8 * CC * NPIX;  // 8*64*1024 floats

  pos_kernel<<<dim3(2048), dim3(256), 0, stream>>>(rel_h, rel_w, pws);
  proj_kernel<<<dim3(8, 4, 24), dim3(256), 0, stream>>>(
      x, wq, bq, wk, bk, wv, bv, qws, kws, vws);
  attn_kernel<<<dim3(16, 8, 8), dim3(256), 0, stream>>>(qws, kws, vws, pws, out);
}

// Round 2
// 273.885 us; speedup vs baseline: 2.5597x; 2.5597x over previous
//
#include <hip/hip_runtime.h>

#define NPIX 1024
#define CC   512
#define DK   64

typedef __attribute__((ext_vector_type(8)))  short s16x8;
typedef __attribute__((ext_vector_type(16))) float f32x16;

union U4 { uint4 u; s16x8 v; };

__device__ __forceinline__ ushort f2bf(float f) {
  uint u = __float_as_uint(f);
  uint r = (u + 0x7fffu + ((u >> 16) & 1u)) >> 16;
  return (ushort)r;
}
__device__ __forceinline__ float bf2f(ushort h) { return __uint_as_float(((uint)h) << 16); }
__device__ __forceinline__ uint pk2(float a, float b) {
  return (uint)f2bf(a) | ((uint)f2bf(b) << 16);
}

__device__ __forceinline__ f32x16 mfma32(s16x8 a, s16x8 b, f32x16 c) {
  return __builtin_amdgcn_mfma_f32_32x32x16_bf16(a, b, c, 0, 0, 0);
}

__device__ __forceinline__ void gl16(const void* g, void* l) {
  __builtin_amdgcn_global_load_lds(
      (const __attribute__((address_space(1))) void*)g,
      (__attribute__((address_space(3))) void*)l, 16, 0, 0);
}

// ---------------------------------------------------------------------------
// pos -> posH/posL[h][n][d]  (bf16 hi/lo, d contiguous, 128B rows)
// ---------------------------------------------------------------------------
__global__ void pos_kernel(const float* __restrict__ rel_h,
                           const float* __restrict__ rel_w,
                           ushort* __restrict__ posH, ushort* __restrict__ posL) {
  int t = blockIdx.x * 256 + threadIdx.x;     // 65536 threads
  int g = t & 7;
  int n = (t >> 3) & (NPIX - 1);
  int h = t >> 13;
  int xw = n >> 5, yh = n & 31;
  ushort hbuf[8], lbuf[8];
#pragma unroll
  for (int j = 0; j < 8; ++j) {
    int d = g * 8 + j;
    float v = rel_h[(h * 64 + d) * 32 + yh] + rel_w[(h * 64 + d) * 32 + xw];
    ushort hi = f2bf(v);
    hbuf[j] = hi;
    lbuf[j] = f2bf(v - bf2f(hi));
  }
  size_t base = ((size_t)(h * NPIX + n)) * 64 + g * 8;
  *(uint4*)&posH[base] = *(uint4*)hbuf;
  *(uint4*)&posL[base] = *(uint4*)lbuf;
}

// ---------------------------------------------------------------------------
// Projection GEMM (fp32 VALU), epilogue writes packed bf16 layouts:
//  p=0 (q): KQh/KQl[bh][n][64+d]      p=1 (k): KQh/KQl[bh][n][d]
//  p=2 (v): Vb[bh][d][n]  (plain bf16)
// ---------------------------------------------------------------------------
__global__ __launch_bounds__(256) void proj_kernel(
    const float* __restrict__ x,
    const float* __restrict__ wq, const float* __restrict__ bq,
    const float* __restrict__ wk, const float* __restrict__ bk,
    const float* __restrict__ wv, const float* __restrict__ bv,
    ushort* __restrict__ KQh, ushort* __restrict__ KQl,
    ushort* __restrict__ Vb) {
  __shared__ __align__(16) float sW[16][128];
  __shared__ __align__(16) float sX[16][128];

  int tid = threadIdx.x;
  int z = blockIdx.z;
  int b = z / 3, p = z % 3;
  const float* W    = (p == 0) ? wq : (p == 1) ? wk : wv;
  const float* bias = (p == 0) ? bq : (p == 1) ? bk : bv;
  const float* X = x + (size_t)b * CC * NPIX;

  int o0 = blockIdx.y * 128;
  int n0 = blockIdx.x * 128;

  float acc[8][8];
#pragma unroll
  for (int i = 0; i < 8; ++i)
#pragma unroll
    for (int j = 0; j < 8; ++j) acc[i][j] = 0.f;

  int ty = tid >> 4;
  int tx = tid & 15;

  for (int c0 = 0; c0 < CC; c0 += 16) {
#pragma unroll
    for (int u = 0; u < 2; ++u) {
      int lin = tid * 2 + u;
      int o = lin >> 2, cq = lin & 3;
      float4 w4 = *(const float4*)&W[(o0 + o) * CC + c0 + cq * 4];
      sW[cq * 4 + 0][o] = w4.x;
      sW[cq * 4 + 1][o] = w4.y;
      sW[cq * 4 + 2][o] = w4.z;
      sW[cq * 4 + 3][o] = w4.w;
    }
#pragma unroll
    for (int u = 0; u < 2; ++u) {
      int lin = tid * 2 + u;
      int kk = lin >> 5, nq = lin & 31;
      *(float4*)&sX[kk][nq * 4] =
          *(const float4*)&X[(c0 + kk) * NPIX + n0 + nq * 4];
    }
    __syncthreads();

#pragma unroll
    for (int kk = 0; kk < 16; ++kk) {
      float4 a0 = *(const float4*)&sW[kk][ty * 8];
      float4 a1 = *(const float4*)&sW[kk][ty * 8 + 4];
      float4 b0 = *(const float4*)&sX[kk][tx * 8];
      float4 b1 = *(const float4*)&sX[kk][tx * 8 + 4];
      float a[8] = {a0.x, a0.y, a0.z, a0.w, a1.x, a1.y, a1.z, a1.w};
      float bb[8] = {b0.x, b0.y, b0.z, b0.w, b1.x, b1.y, b1.z, b1.w};
#pragma unroll
      for (int i = 0; i < 8; ++i)
#pragma unroll
        for (int j = 0; j < 8; ++j) acc[i][j] = fmaf(a[i], bb[j], acc[i][j]);
    }
    __syncthreads();
  }

  int obase = o0 + ty * 8;
  int hh = obase >> 6;          // head (constant across i: 8-aligned within 64)
  int dbase = obase & 63;
  int bh = b * 8 + hh;
  float bias8[8];
#pragma unroll
  for (int i = 0; i < 8; ++i) bias8[i] = bias[obase + i];

  if (p == 2) {
    // Vb[bh][d][n]: per i, 8 consecutive n
#pragma unroll
    for (int i = 0; i < 8; ++i) {
      ushort h8[8];
#pragma unroll
      for (int j = 0; j < 8; ++j) h8[j] = f2bf(acc[i][j] + bias8[i]);
      size_t base = ((size_t)(bh * 64 + dbase + i)) * NPIX + n0 + tx * 8;
      *(uint4*)&Vb[base] = *(uint4*)h8;
    }
  } else {
    int kkoff = (p == 0) ? 64 + dbase : dbase;
    // KQ[bh][n][kk]: per j (n), 8 consecutive kk (across i)
#pragma unroll
    for (int j = 0; j < 8; ++j) {
      ushort h8[8], l8[8];
#pragma unroll
      for (int i = 0; i < 8; ++i) {
        float v = acc[i][j] + bias8[i];
        ushort hi = f2bf(v);
        h8[i] = hi;
        l8[i] = f2bf(v - bf2f(hi));
      }
      size_t base = ((size_t)bh * NPIX + n0 + tx * 8 + j) * 128 + kkoff;
      *(uint4*)&KQh[base] = *(uint4*)h8;
      *(uint4*)&KQl[base] = *(uint4*)l8;
    }
  }
}

// ---------------------------------------------------------------------------
// Fused MFMA attention.
// Block: 256 thr = 4 waves; wave owns 32 queries; block = 128 queries, one bh.
// Keys streamed in 128-chunks: LDS sKh/sKl ([key][128kk], swizzled) + sV.
// S-tile (32 keys x 32 queries) via mfma_f32_32x32x16_bf16, compensated hi/lo.
// Online softmax in-register (lane owns one query column), PV via bf16 mfma.
// ---------------------------------------------------------------------------
__global__ __launch_bounds__(256, 2) void attn_kernel(
    const ushort* __restrict__ KQh, const ushort* __restrict__ KQl,
    const ushort* __restrict__ posH, const ushort* __restrict__ posL,
    const ushort* __restrict__ Vb, float* __restrict__ out) {
  __shared__ __align__(16) ushort sKh[128 * 128];
  __shared__ __align__(16) ushort sKl[128 * 128];
  __shared__ __align__(16) ushort sV[64 * 128];

  int tid = threadIdx.x;
  int lane = tid & 63;
  int w = tid >> 6;

  // XCD-bijective swizzle: 512 blocks, 8 XCDs -> 64 contiguous wg per XCD
  int bid = blockIdx.x;
  int wg = (bid & 7) * 64 + (bid >> 3);
  int bh = wg >> 3;
  int qb = wg & 7;
  int h = bh & 7;

  int col = lane & 31;
  int half = lane >> 5;
  int q0 = qb * 128 + w * 32;
  int q = q0 + col;

  // ---- resident Q-side B-fragments (hi/lo), 8 kk-steps ----
  uint4 bqh[8], bql[8];
  {
    const ushort* rowQh = KQh + ((size_t)bh * NPIX + q) * 128;
    const ushort* rowQl = KQl + ((size_t)bh * NPIX + q) * 128;
#pragma unroll
    for (int s = 0; s < 4; ++s) {
      int off = 64 + s * 16 + half * 8;
      bqh[s] = *(const uint4*)(rowQh + off);
      bql[s] = *(const uint4*)(rowQl + off);
    }
    const ushort* rowPh = posH + ((size_t)(h * NPIX + q)) * 64;
    const ushort* rowPl = posL + ((size_t)(h * NPIX + q)) * 64;
#pragma unroll
    for (int s = 4; s < 8; ++s) {
      int off = (s - 4) * 16 + half * 8;
      bqh[s] = *(const uint4*)(rowPh + off);
      bql[s] = *(const uint4*)(rowPl + off);
    }
  }

  f32x16 oacc[2];
#pragma unroll
  for (int t = 0; t < 2; ++t)
#pragma unroll
    for (int r = 0; r < 16; ++r) oacc[t][r] = 0.f;
  float m_ = -1e30f, l_ = 0.f;

  int srow = lane >> 4;        // staging: row-within-4
  int sslot = lane & 15;       // staging: 16B slot within row

#pragma unroll 1
  for (int k0 = 0; k0 < NPIX; k0 += 128) {
    // ---- stage chunk: KQh/KQl (32KB each) + V (16KB), swizzled source ----
#pragma unroll
    for (int i = 0; i < 8; ++i) {
      int row = w * 32 + i * 4 + srow;
      size_t goff = ((size_t)bh * NPIX + k0 + row) * 128 + ((sslot ^ (row & 15)) << 3);
      char* ldst = (char*)sKh + (w * 32 + i * 4) * 256;
      gl16(KQh + goff, ldst);
    }
#pragma unroll
    for (int i = 0; i < 8; ++i) {
      int row = w * 32 + i * 4 + srow;
      size_t goff = ((size_t)bh * NPIX + k0 + row) * 128 + ((sslot ^ (row & 15)) << 3);
      char* ldst = (char*)sKl + (w * 32 + i * 4) * 256;
      gl16(KQl + goff, ldst);
    }
#pragma unroll
    for (int i = 0; i < 4; ++i) {
      int d = w * 16 + i * 4 + srow;
      size_t goff = ((size_t)(bh * 64 + d)) * NPIX + k0 + ((sslot ^ (d & 15)) << 3);
      char* ldst = (char*)sV + (w * 16 + i * 4) * 256;
      gl16(Vb + goff, ldst);
    }
    __syncthreads();

    // ---- S phase: 4 key-tiles x 8 kk-steps x 3 compensated products ----
    f32x16 sa[4];
#pragma unroll
    for (int t = 0; t < 4; ++t)
#pragma unroll
      for (int r = 0; r < 16; ++r) sa[t][r] = 0.f;

#pragma unroll
    for (int s = 0; s < 8; ++s) {
      U4 ubh, ubl;
      ubh.u = bqh[s];
      ubl.u = bql[s];
#pragma unroll
      for (int t = 0; t < 4; ++t) {
        int row = t * 32 + col;
        int slot = ((s * 2 + half) ^ (row & 15)) << 4;
        const s16x8 ah = *(const s16x8*)((const char*)sKh + row * 256 + slot);
        const s16x8 al = *(const s16x8*)((const char*)sKl + row * 256 + slot);
        sa[t] = mfma32(ah, ubh.v, sa[t]);
        sa[t] = mfma32(ah, ubl.v, sa[t]);
        sa[t] = mfma32(al, ubh.v, sa[t]);
      }
    }

    // ---- online softmax (lane owns one query column; 64 keys here,
    //      partner lane l^32 owns the other 64 of the 128-chunk) ----
    float mx = sa[0][0];
#pragma unroll
    for (int t = 0; t < 4; ++t)
#pragma unroll
      for (int r = 0; r < 16; ++r) mx = fmaxf(mx, sa[t][r]);
    mx = fmaxf(mx, __shfl_xor(mx, 32));
    float mn = fmaxf(m_, mx);
    float sc = __expf(m_ - mn);
    float ssum = 0.f;
#pragma unroll
    for (int t = 0; t < 4; ++t)
#pragma unroll
      for (int r = 0; r < 16; ++r) {
        float pv = __expf(sa[t][r] - mn);
        sa[t][r] = pv;
        ssum += pv;
      }
    ssum += __shfl_xor(ssum, 32);
    l_ = l_ * sc + ssum;
    m_ = mn;
#pragma unroll
    for (int t = 0; t < 2; ++t)
#pragma unroll
      for (int r = 0; r < 16; ++r) oacc[t][r] *= sc;

    // ---- PV: per 32-key tile build bf16 P-fragments, 2 k-steps x 2 d-tiles ----
#pragma unroll
    for (int t = 0; t < 4; ++t) {
      uint ua[4], ub[4], xa[4], xb[4];
#pragma unroll
      for (int g = 0; g < 4; ++g) {
        ua[g] = pk2(sa[t][4 * g + 0], sa[t][4 * g + 1]);
        ub[g] = pk2(sa[t][4 * g + 2], sa[t][4 * g + 3]);
      }
#pragma unroll
      for (int g = 0; g < 4; ++g) {
        xa[g] = __shfl_xor(ua[g], 32);
        xb[g] = __shfl_xor(ub[g], 32);
      }
#pragma unroll
      for (int st = 0; st < 2; ++st) {
        int g = st * 2 + half;
        U4 pf;
        if (half == 0) {
          pf.u.x = ua[g]; pf.u.y = ub[g]; pf.u.z = xa[g]; pf.u.w = xb[g];
        } else {
          pf.u.x = xa[g]; pf.u.y = xb[g]; pf.u.z = ua[g]; pf.u.w = ub[g];
        }
#pragma unroll
        for (int dt = 0; dt < 2; ++dt) {
          int d = dt * 32 + col;
          int slot = ((t * 4 + st * 2 + half) ^ (d & 15)) << 4;
          const s16x8 vf = *(const s16x8*)((const char*)sV + d * 256 + slot);
          oacc[dt] = mfma32(vf, pf.v, oacc[dt]);
        }
      }
    }
    __syncthreads();
  }

  // ---- epilogue: normalize, store fp32 ----
  float inv = 1.0f / l_;
#pragma unroll
  for (int dt = 0; dt < 2; ++dt)
#pragma unroll
    for (int r = 0; r < 16; ++r) {
      int d = dt * 32 + (r & 3) + 8 * (r >> 2) + 4 * half;
      out[((size_t)(bh * 64 + d) << 10) + q] = oacc[dt][r] * inv;
    }
}

// ---------------------------------------------------------------------------
extern "C" void kernel_launch(void* const* d_in, const int* in_sizes, int n_in,
                              void* d_out, int out_size, void* d_ws, size_t ws_size,
                              hipStream_t stream) {
  const float* x     = (const float*)d_in[0];
  const float* wq    = (const float*)d_in[1];
  const float* bq    = (const float*)d_in[2];
  const float* wk    = (const float*)d_in[3];
  const float* bk    = (const float*)d_in[4];
  const float* wv    = (const float*)d_in[5];
  const float* bv    = (const float*)d_in[6];
  const float* rel_h = (const float*)d_in[7];
  const float* rel_w = (const float*)d_in[8];
  float* out = (float*)d_out;

  // ws layout (bytes): KQh 16MB | KQl 16MB | Vb 8MB | posH 1MB | posL 1MB
  char* ws = (char*)d_ws;
  ushort* KQh  = (ushort*)(ws);
  ushort* KQl  = (ushort*)(ws + (size_t)16 * 1024 * 1024);
  ushort* Vb   = (ushort*)(ws + (size_t)32 * 1024 * 1024);
  ushort* posH = (ushort*)(ws + (size_t)40 * 1024 * 1024);
  ushort* posL = (ushort*)(ws + (size_t)41 * 1024 * 1024);

  pos_kernel<<<dim3(256), dim3(256), 0, stream>>>(rel_h, rel_w, posH, posL);
  proj_kernel<<<dim3(8, 4, 24), dim3(256), 0, stream>>>(
      x, wq, bq, wk, bk, wv, bv, KQh, KQl, Vb);
  attn_kernel<<<dim3(512), dim3(256), 0, stream>>>(KQh, KQl, posH, posL, Vb, out);
}

// Round 3
// 135.773 us; speedup vs baseline: 5.1635x; 2.0172x over previous
//
#include <hip/hip_runtime.h>

#define NPIX 1024
#define CC   512
#define DK   64

typedef __attribute__((ext_vector_type(8)))  short s16x8;
typedef __attribute__((ext_vector_type(16))) float f32x16;

union U4 { uint4 u; s16x8 v; };

__device__ __forceinline__ ushort f2bf(float f) {
  uint u = __float_as_uint(f);
  uint r = (u + 0x7fffu + ((u >> 16) & 1u)) >> 16;
  return (ushort)r;
}
__device__ __forceinline__ float bf2f(ushort h) { return __uint_as_float(((uint)h) << 16); }
__device__ __forceinline__ uint pk2(float a, float b) {
  return (uint)f2bf(a) | ((uint)f2bf(b) << 16);
}

__device__ __forceinline__ f32x16 mfma32(s16x8 a, s16x8 b, f32x16 c) {
  return __builtin_amdgcn_mfma_f32_32x32x16_bf16(a, b, c, 0, 0, 0);
}

__device__ __forceinline__ void gl16(const void* g, void* l) {
  __builtin_amdgcn_global_load_lds(
      (const __attribute__((address_space(1))) void*)g,
      (__attribute__((address_space(3))) void*)l, 16, 0, 0);
}

// ---------------------------------------------------------------------------
// pos -> posH/posL[h][n][d]  (bf16 hi/lo, d contiguous, 128B rows)
// ---------------------------------------------------------------------------
__global__ void pos_kernel(const float* __restrict__ rel_h,
                           const float* __restrict__ rel_w,
                           ushort* __restrict__ posH, ushort* __restrict__ posL) {
  int t = blockIdx.x * 256 + threadIdx.x;     // 65536 threads
  int g = t & 7;
  int n = (t >> 3) & (NPIX - 1);
  int h = t >> 13;
  int xw = n >> 5, yh = n & 31;
  ushort hbuf[8], lbuf[8];
#pragma unroll
  for (int j = 0; j < 8; ++j) {
    int d = g * 8 + j;
    float v = rel_h[(h * 64 + d) * 32 + yh] + rel_w[(h * 64 + d) * 32 + xw];
    ushort hi = f2bf(v);
    hbuf[j] = hi;
    lbuf[j] = f2bf(v - bf2f(hi));
  }
  size_t base = ((size_t)(h * NPIX + n)) * 64 + g * 8;
  *(uint4*)&posH[base] = *(uint4*)hbuf;
  *(uint4*)&posL[base] = *(uint4*)lbuf;
}

// ---------------------------------------------------------------------------
// W conversion: wq/wk/wv [o][c] fp32 -> Wh/Wl[p][o][c] bf16 hi/lo
// ---------------------------------------------------------------------------
__global__ __launch_bounds__(256) void cvt_w_kernel(
    const float* __restrict__ wq, const float* __restrict__ wk,
    const float* __restrict__ wv,
    ushort* __restrict__ Wh, ushort* __restrict__ Wl) {
  int lin8 = blockIdx.x * 256 + threadIdx.x;    // 98304 threads, 8 elems each
  int p = lin8 >> 15;
  int o = (lin8 & 32767) >> 6;
  int co = lin8 & 63;
  const float* Wsrc = (p == 0) ? wq : (p == 1) ? wk : wv;
  const float* src = &Wsrc[o * CC + co * 8];
  float4 f0 = *(const float4*)src;
  float4 f1 = *(const float4*)(src + 4);
  float f[8] = {f0.x, f0.y, f0.z, f0.w, f1.x, f1.y, f1.z, f1.w};
  ushort h8[8], l8[8];
#pragma unroll
  for (int j = 0; j < 8; ++j) {
    ushort hi = f2bf(f[j]);
    h8[j] = hi;
    l8[j] = f2bf(f[j] - bf2f(hi));
  }
  size_t dst = ((size_t)(p * CC + o)) * CC + co * 8;
  *(uint4*)&Wh[dst] = *(uint4*)h8;
  *(uint4*)&Wl[dst] = *(uint4*)l8;
}

// ---------------------------------------------------------------------------
// X transpose+convert: x[b][c][n] fp32 -> Xh/Xl[b][n][c] bf16 hi/lo
// thread: one n, one 8-c octet. reads coalesced across lanes (consecutive n).
// ---------------------------------------------------------------------------
__global__ __launch_bounds__(256) void cvt_x_kernel(
    const float* __restrict__ x,
    ushort* __restrict__ Xh, ushort* __restrict__ Xl) {
  int t = blockIdx.x * 256 + threadIdx.x;      // 524288 threads
  int nl = t & (NPIX - 1);
  int rest = t >> 10;
  int co = rest & 63;
  int b = rest >> 6;
  ushort h8[8], l8[8];
#pragma unroll
  for (int j = 0; j < 8; ++j) {
    float v = x[(((size_t)(b * CC + co * 8 + j)) << 10) + nl];
    ushort hi = f2bf(v);
    h8[j] = hi;
    l8[j] = f2bf(v - bf2f(hi));
  }
  size_t dst = (((size_t)(b * NPIX + nl)) << 9) + co * 8;
  *(uint4*)&Xh[dst] = *(uint4*)h8;
  *(uint4*)&Xl[dst] = *(uint4*)l8;
}

// ---------------------------------------------------------------------------
// Projection GEMM via MFMA. Y[o,n] = sum_c W[o,c] X[c,n] + bias[o]
// Tile 128o x 128n, K=512 in BK=64 chunks. 4 waves (2x2 of 64x64).
// LDS rows 256B: [hi 8 slots | lo 8 slots] x 16B, swizzled slot^(row&15).
// p<2 (q,k): compensated 3-product, D[n][o] -> KQh/KQl[bh][n][kk]
// p==2 (v): plain hi product,      D[o][n] -> Vb[bh][d][n]
// ---------------------------------------------------------------------------
__global__ __launch_bounds__(256, 2) void proj_kernel(
    const ushort* __restrict__ Xh, const ushort* __restrict__ Xl,
    const ushort* __restrict__ Wh, const ushort* __restrict__ Wl,
    const float* __restrict__ bq, const float* __restrict__ bk,
    const float* __restrict__ bv,
    ushort* __restrict__ KQh, ushort* __restrict__ KQl,
    ushort* __restrict__ Vb) {
  __shared__ __align__(16) ushort sW[128 * 128];
  __shared__ __align__(16) ushort sX[128 * 128];

  int tid = threadIdx.x;
  int lane = tid & 63;
  int w = tid >> 6;
  int col = lane & 31;
  int half = lane >> 5;
  int srow = lane >> 4;
  int sslot = lane & 15;

  int z = blockIdx.z;
  int b = z / 3, p = z % 3;
  const float* bias = (p == 0) ? bq : (p == 1) ? bk : bv;

  int n0 = blockIdx.x * 128;
  int o0 = blockIdx.y * 128;
  int wo = w >> 1;      // wave o-half
  int wn = w & 1;       // wave n-half

  f32x16 acc[2][2];
#pragma unroll
  for (int i = 0; i < 2; ++i)
#pragma unroll
    for (int j = 0; j < 2; ++j)
#pragma unroll
      for (int r = 0; r < 16; ++r) acc[i][j][r] = 0.f;

  const char* Abuf = (const char*)((p < 2) ? sX : sW);
  const char* Bbuf = (const char*)((p < 2) ? sW : sX);
  int wm = (p < 2) ? wn : wo;   // wave coord along D-rows
  int wc = (p < 2) ? wo : wn;   // wave coord along D-cols

#pragma unroll 1
  for (int c0 = 0; c0 < CC; c0 += 64) {
    // ---- stage W tile ----
#pragma unroll
    for (int i = 0; i < 8; ++i) {
      int rbase = (i * 4 + w) * 4;
      int row = rbase + srow;
      int j = sslot ^ (row & 15);
      int jc = j & 7;
      const ushort* src = (j < 8 || p == 2) ? Wh : Wl;
      size_t g = ((size_t)(p * CC + o0 + row)) * CC + c0 + jc * 8;
      gl16(src + g, (char*)sW + rbase * 256);
    }
    // ---- stage X tile ----
#pragma unroll
    for (int i = 0; i < 8; ++i) {
      int rbase = (i * 4 + w) * 4;
      int row = rbase + srow;
      int j = sslot ^ (row & 15);
      int jc = j & 7;
      const ushort* src = (j < 8 || p == 2) ? Xh : Xl;
      size_t g = ((size_t)(b * NPIX + n0 + row)) * CC + c0 + jc * 8;
      gl16(src + g, (char*)sX + rbase * 256);
    }
    __syncthreads();

#pragma unroll
    for (int s = 0; s < 4; ++s) {
      s16x8 ah[2], al[2], bh_[2], bl_[2];
#pragma unroll
      for (int mt = 0; mt < 2; ++mt) {
        int row = wm * 64 + mt * 32 + col;
        int sh = ((s * 2 + half) ^ (row & 15)) << 4;
        ah[mt] = *(const s16x8*)(Abuf + row * 256 + sh);
        if (p < 2) {
          int sl = ((8 + s * 2 + half) ^ (row & 15)) << 4;
          al[mt] = *(const s16x8*)(Abuf + row * 256 + sl);
        }
      }
#pragma unroll
      for (int ct = 0; ct < 2; ++ct) {
        int row = wc * 64 + ct * 32 + col;
        int sh = ((s * 2 + half) ^ (row & 15)) << 4;
        bh_[ct] = *(const s16x8*)(Bbuf + row * 256 + sh);
        if (p < 2) {
          int sl = ((8 + s * 2 + half) ^ (row & 15)) << 4;
          bl_[ct] = *(const s16x8*)(Bbuf + row * 256 + sl);
        }
      }
#pragma unroll
      for (int mt = 0; mt < 2; ++mt)
#pragma unroll
        for (int ct = 0; ct < 2; ++ct) {
          acc[mt][ct] = mfma32(ah[mt], bh_[ct], acc[mt][ct]);
          if (p < 2) {
            acc[mt][ct] = mfma32(ah[mt], bl_[ct], acc[mt][ct]);
            acc[mt][ct] = mfma32(al[mt], bh_[ct], acc[mt][ct]);
          }
        }
    }
    __syncthreads();
  }

  // ---- epilogue ----
  if (p < 2) {
    // D[m=n-pixel][col=o]; write KQ[bh][n][kk], kk = (p==0?64:0)+d
#pragma unroll
    for (int ct = 0; ct < 2; ++ct) {
      int o = o0 + wo * 64 + ct * 32 + col;
      int bh = b * 8 + (o >> 6);
      int kk = ((p == 0) ? 64 : 0) + (o & 63);
      float bias_v = bias[o];
#pragma unroll
      for (int mt = 0; mt < 2; ++mt) {
        int nbase = n0 + wn * 64 + mt * 32;
#pragma unroll
        for (int r = 0; r < 16; ++r) {
          int n = nbase + (r & 3) + 8 * (r >> 2) + 4 * half;
          float v = acc[mt][ct][r] + bias_v;
          ushort hi = f2bf(v);
          ushort lo = f2bf(v - bf2f(hi));
          size_t addr = (((size_t)bh << 10) + n) * 128 + kk;
          KQh[addr] = hi;
          KQl[addr] = lo;
        }
      }
    }
  } else {
    // D[m=o][col=n-pixel]; write Vb[bh*64+d][n]
#pragma unroll
    for (int ct = 0; ct < 2; ++ct) {
      int n = n0 + wn * 64 + ct * 32 + col;
#pragma unroll
      for (int mt = 0; mt < 2; ++mt) {
        int obase = o0 + wo * 64 + mt * 32;
#pragma unroll
        for (int r = 0; r < 16; ++r) {
          int o = obase + (r & 3) + 8 * (r >> 2) + 4 * half;
          int bh = b * 8 + (o >> 6);
          int d = o & 63;
          float v = acc[mt][ct][r] + bias[o];
          Vb[(((size_t)(bh * 64 + d)) << 10) + n] = f2bf(v);
        }
      }
    }
  }
}

// ---------------------------------------------------------------------------
// Fused MFMA attention (unchanged from round 2).
// ---------------------------------------------------------------------------
__global__ __launch_bounds__(256, 2) void attn_kernel(
    const ushort* __restrict__ KQh, const ushort* __restrict__ KQl,
    const ushort* __restrict__ posH, const ushort* __restrict__ posL,
    const ushort* __restrict__ Vb, float* __restrict__ out) {
  __shared__ __align__(16) ushort sKh[128 * 128];
  __shared__ __align__(16) ushort sKl[128 * 128];
  __shared__ __align__(16) ushort sV[64 * 128];

  int tid = threadIdx.x;
  int lane = tid & 63;
  int w = tid >> 6;

  int bid = blockIdx.x;
  int wg = (bid & 7) * 64 + (bid >> 3);
  int bh = wg >> 3;
  int qb = wg & 7;
  int h = bh & 7;

  int col = lane & 31;
  int half = lane >> 5;
  int q0 = qb * 128 + w * 32;
  int q = q0 + col;

  uint4 bqh[8], bql[8];
  {
    const ushort* rowQh = KQh + ((size_t)bh * NPIX + q) * 128;
    const ushort* rowQl = KQl + ((size_t)bh * NPIX + q) * 128;
#pragma unroll
    for (int s = 0; s < 4; ++s) {
      int off = 64 + s * 16 + half * 8;
      bqh[s] = *(const uint4*)(rowQh + off);
      bql[s] = *(const uint4*)(rowQl + off);
    }
    const ushort* rowPh = posH + ((size_t)(h * NPIX + q)) * 64;
    const ushort* rowPl = posL + ((size_t)(h * NPIX + q)) * 64;
#pragma unroll
    for (int s = 4; s < 8; ++s) {
      int off = (s - 4) * 16 + half * 8;
      bqh[s] = *(const uint4*)(rowPh + off);
      bql[s] = *(const uint4*)(rowPl + off);
    }
  }

  f32x16 oacc[2];
#pragma unroll
  for (int t = 0; t < 2; ++t)
#pragma unroll
    for (int r = 0; r < 16; ++r) oacc[t][r] = 0.f;
  float m_ = -1e30f, l_ = 0.f;

  int srow = lane >> 4;
  int sslot = lane & 15;

#pragma unroll 1
  for (int k0 = 0; k0 < NPIX; k0 += 128) {
#pragma unroll
    for (int i = 0; i < 8; ++i) {
      int row = w * 32 + i * 4 + srow;
      size_t goff = ((size_t)bh * NPIX + k0 + row) * 128 + ((sslot ^ (row & 15)) << 3);
      char* ldst = (char*)sKh + (w * 32 + i * 4) * 256;
      gl16(KQh + goff, ldst);
    }
#pragma unroll
    for (int i = 0; i < 8; ++i) {
      int row = w * 32 + i * 4 + srow;
      size_t goff = ((size_t)bh * NPIX + k0 + row) * 128 + ((sslot ^ (row & 15)) << 3);
      char* ldst = (char*)sKl + (w * 32 + i * 4) * 256;
      gl16(KQl + goff, ldst);
    }
#pragma unroll
    for (int i = 0; i < 4; ++i) {
      int d = w * 16 + i * 4 + srow;
      size_t goff = ((size_t)(bh * 64 + d)) * NPIX + k0 + ((sslot ^ (d & 15)) << 3);
      char* ldst = (char*)sV + (w * 16 + i * 4) * 256;
      gl16(Vb + goff, ldst);
    }
    __syncthreads();

    f32x16 sa[4];
#pragma unroll
    for (int t = 0; t < 4; ++t)
#pragma unroll
      for (int r = 0; r < 16; ++r) sa[t][r] = 0.f;

#pragma unroll
    for (int s = 0; s < 8; ++s) {
      U4 ubh, ubl;
      ubh.u = bqh[s];
      ubl.u = bql[s];
#pragma unroll
      for (int t = 0; t < 4; ++t) {
        int row = t * 32 + col;
        int slot = ((s * 2 + half) ^ (row & 15)) << 4;
        const s16x8 ah = *(const s16x8*)((const char*)sKh + row * 256 + slot);
        const s16x8 al = *(const s16x8*)((const char*)sKl + row * 256 + slot);
        sa[t] = mfma32(ah, ubh.v, sa[t]);
        sa[t] = mfma32(ah, ubl.v, sa[t]);
        sa[t] = mfma32(al, ubh.v, sa[t]);
      }
    }

    float mx = sa[0][0];
#pragma unroll
    for (int t = 0; t < 4; ++t)
#pragma unroll
      for (int r = 0; r < 16; ++r) mx = fmaxf(mx, sa[t][r]);
    mx = fmaxf(mx, __shfl_xor(mx, 32));
    float mn = fmaxf(m_, mx);
    float sc = __expf(m_ - mn);
    float ssum = 0.f;
#pragma unroll
    for (int t = 0; t < 4; ++t)
#pragma unroll
      for (int r = 0; r < 16; ++r) {
        float pv = __expf(sa[t][r] - mn);
        sa[t][r] = pv;
        ssum += pv;
      }
    ssum += __shfl_xor(ssum, 32);
    l_ = l_ * sc + ssum;
    m_ = mn;
#pragma unroll
    for (int t = 0; t < 2; ++t)
#pragma unroll
      for (int r = 0; r < 16; ++r) oacc[t][r] *= sc;

#pragma unroll
    for (int t = 0; t < 4; ++t) {
      uint ua[4], ub[4], xa[4], xb[4];
#pragma unroll
      for (int g = 0; g < 4; ++g) {
        ua[g] = pk2(sa[t][4 * g + 0], sa[t][4 * g + 1]);
        ub[g] = pk2(sa[t][4 * g + 2], sa[t][4 * g + 3]);
      }
#pragma unroll
      for (int g = 0; g < 4; ++g) {
        xa[g] = __shfl_xor(ua[g], 32);
        xb[g] = __shfl_xor(ub[g], 32);
      }
#pragma unroll
      for (int st = 0; st < 2; ++st) {
        int g = st * 2 + half;
        U4 pf;
        if (half == 0) {
          pf.u.x = ua[g]; pf.u.y = ub[g]; pf.u.z = xa[g]; pf.u.w = xb[g];
        } else {
          pf.u.x = xa[g]; pf.u.y = xb[g]; pf.u.z = ua[g]; pf.u.w = ub[g];
        }
#pragma unroll
        for (int dt = 0; dt < 2; ++dt) {
          int d = dt * 32 + col;
          int slot = ((t * 4 + st * 2 + half) ^ (d & 15)) << 4;
          const s16x8 vf = *(const s16x8*)((const char*)sV + d * 256 + slot);
          oacc[dt] = mfma32(vf, pf.v, oacc[dt]);
        }
      }
    }
    __syncthreads();
  }

  float inv = 1.0f / l_;
#pragma unroll
  for (int dt = 0; dt < 2; ++dt)
#pragma unroll
    for (int r = 0; r < 16; ++r) {
      int d = dt * 32 + (r & 3) + 8 * (r >> 2) + 4 * half;
      out[((size_t)(bh * 64 + d) << 10) + q] = oacc[dt][r] * inv;
    }
}

// ---------------------------------------------------------------------------
extern "C" void kernel_launch(void* const* d_in, const int* in_sizes, int n_in,
                              void* d_out, int out_size, void* d_ws, size_t ws_size,
                              hipStream_t stream) {
  const float* x     = (const float*)d_in[0];
  const float* wq    = (const float*)d_in[1];
  const float* bq    = (const float*)d_in[2];
  const float* wk    = (const float*)d_in[3];
  const float* bk    = (const float*)d_in[4];
  const float* wv    = (const float*)d_in[5];
  const float* bv    = (const float*)d_in[6];
  const float* rel_h = (const float*)d_in[7];
  const float* rel_w = (const float*)d_in[8];
  float* out = (float*)d_out;

  // ws layout (MB): KQh 16 | KQl 16 | Vb 8 | posH 1 | posL 1 | Xh 8 | Xl 8 | Wh 1.5 | Wl 1.5
  const size_t MB = 1024 * 1024;
  char* ws = (char*)d_ws;
  ushort* KQh  = (ushort*)(ws);
  ushort* KQl  = (ushort*)(ws + 16 * MB);
  ushort* Vb   = (ushort*)(ws + 32 * MB);
  ushort* posH = (ushort*)(ws + 40 * MB);
  ushort* posL = (ushort*)(ws + 41 * MB);
  ushort* Xh   = (ushort*)(ws + 42 * MB);
  ushort* Xl   = (ushort*)(ws + 50 * MB);
  ushort* Wh   = (ushort*)(ws + 58 * MB);
  ushort* Wl   = (ushort*)(ws + 58 * MB + 1572864);

  pos_kernel<<<dim3(256), dim3(256), 0, stream>>>(rel_h, rel_w, posH, posL);
  cvt_w_kernel<<<dim3(384), dim3(256), 0, stream>>>(wq, wk, wv, Wh, Wl);
  cvt_x_kernel<<<dim3(2048), dim3(256), 0, stream>>>(x, Xh, Xl);
  proj_kernel<<<dim3(8, 4, 24), dim3(256), 0, stream>>>(
      Xh, Xl, Wh, Wl, bq, bk, bv, KQh, KQl, Vb);
  attn_kernel<<<dim3(512), dim3(256), 0, stream>>>(KQh, KQl, posH, posL, Vb, out);
}